// Round 1
// baseline (438.980 us; speedup 1.0000x reference)
//
#include <hip/hip_runtime.h>
#include <stdint.h>

typedef unsigned short u16;
typedef __attribute__((ext_vector_type(8))) short    bf16x8;   // 8 bf16 in 4 VGPRs
typedef __attribute__((ext_vector_type(4))) float    f32x4;

// ---------- helpers ----------
__device__ __forceinline__ u16 f2bf(float f) {           // fp32 -> bf16, round-nearest-even
    unsigned u = __float_as_uint(f);
    u = (u + 0x7fffu + ((u >> 16) & 1u)) >> 16;
    return (u16)u;
}

// ---------- fp32 -> bf16 cast (vectorized) ----------
__global__ __launch_bounds__(256) void cast_bf16_kernel(const float* __restrict__ in,
                                                        u16* __restrict__ out, int n4) {
    int i = blockIdx.x * 256 + threadIdx.x;
    if (i < n4) {
        float4 f = ((const float4*)in)[i];
        ushort4 o;
        o.x = f2bf(f.x); o.y = f2bf(f.y); o.z = f2bf(f.z); o.w = f2bf(f.w);
        ((ushort4*)out)[i] = o;
    }
}

// cast the three weight matrices into one concatenated [2304][768] bf16 buffer
__global__ __launch_bounds__(256) void cast3_bf16_kernel(const float* __restrict__ w0,
                                                         const float* __restrict__ w1,
                                                         const float* __restrict__ w2,
                                                         u16* __restrict__ out) {
    const float* src = (blockIdx.y == 0) ? w0 : (blockIdx.y == 1) ? w1 : w2;
    int i = blockIdx.x * 256 + threadIdx.x;          // 576*256 = 147456 = 768*768/4
    float4 f = ((const float4*)src)[i];
    ushort4 o;
    o.x = f2bf(f.x); o.y = f2bf(f.y); o.z = f2bf(f.z); o.w = f2bf(f.w);
    ((ushort4*)out)[(size_t)blockIdx.y * 147456 + i] = o;
}

// ---------- bf16 32x32-tiled transpose: Vt[b][e][s] = V[b][s][e] (ld_in=2304) ----------
// also zeroes the rowsum buffer (it aliases the dead weight buffer; runs after proj GEMM)
__global__ __launch_bounds__(256) void transpose_bf16_kernel(const u16* __restrict__ V,
                                                             u16* __restrict__ Vt,
                                                             float* __restrict__ rsum) {
    __shared__ u16 tile[32][33];
    const int t = threadIdx.x;
    if (blockIdx.x == 0 && blockIdx.z == 0) {
        int idx = blockIdx.y * 256 + t;
        if (idx < 16384) rsum[idx] = 0.f;
    }
    const size_t z = blockIdx.z;
    const u16* Vb  = V  + z * (size_t)4096 * 2304;
    u16*       Vtb = Vt + z * (size_t)768 * 4096;
    const int c0 = blockIdx.x * 32;           // D (col) tile
    const int r0 = blockIdx.y * 32;           // S (row) tile
    const int lr = t >> 3;                    // 0..31
    const int lc = (t & 7) * 4;               // 0..28
    ushort4 in = *(const ushort4*)&Vb[(size_t)(r0 + lr) * 2304 + c0 + lc];
    tile[lr][lc + 0] = in.x; tile[lr][lc + 1] = in.y;
    tile[lr][lc + 2] = in.z; tile[lr][lc + 3] = in.w;
    __syncthreads();
    ushort4 o;
    o.x = tile[lc + 0][lr]; o.y = tile[lc + 1][lr];
    o.z = tile[lc + 2][lr]; o.w = tile[lc + 3][lr];
    *(ushort4*)&Vtb[(size_t)(c0 + lr) * 4096 + r0 + lc] = o;
}

// ---------- 2-phase GEMM (kept for QKV projection only; R5/R6-proven thin tile) ----------
template <int EPI, int WN, int NBX, int GRP, int NGRID, int NBY, int MINW>
__global__ __launch_bounds__(256, MINW) void gemm_bt_kernel(
        const u16* __restrict__ A, const u16* __restrict__ B, void* __restrict__ Cv,
        const float* __restrict__ b0, const float* __restrict__ b1, const float* __restrict__ b2,
        float* __restrict__ rs, float s2, int K,
        int lda, int ldb, int ldc, long batchA, long batchB, long batchC) {
    __shared__ __align__(16) u16 As[128 * 64];
    __shared__ __align__(16) u16 Bs[32 * WN * 64];

    constexpr int SPX = NGRID / (8 * NBX);        // strips per XCD
    const int lin = blockIdx.x;
    const int c = lin & 7, p = lin >> 3;
    const int bxi = p % GRP;
    const int rest = p / GRP;
    const int s = rest % SPX;
    const int g = rest / SPX;
    const int bx = g * GRP + bxi;
    const int strip = c * SPX + s;
    const int by = strip % NBY;
    const int bz = strip / NBY;

    const int t = threadIdx.x;
    const long z = bz;
    const u16* Ab = A + z * batchA + (long)by * 128 * lda;
    const u16* Bb = B + z * batchB + (long)bx * (32 * WN) * ldb;

    const int lane = t & 63;
    const int wave = t >> 6;
    const int wm = wave >> 1, wn = wave & 1;      // 2x2 wave grid
    const int quad = lane >> 4;
    const int frow = lane & 15;
    const int cc0 = quad ^ (frow & 7);            // swizzled chunk col for k-chunk 0

    f32x4 acc[4][WN];
#pragma unroll
    for (int i = 0; i < 4; i++)
#pragma unroll
        for (int j = 0; j < WN; j++)
#pragma unroll
            for (int e = 0; e < 4; e++) acc[i][j][e] = 0.f;

    int srow[WN], scol[WN];
#pragma unroll
    for (int j = 0; j < WN; j++) {
        const int d = t + j * 256;
        srow[j] = d >> 3;
        scol[j] = ((d & 7) ^ (srow[j] & 7)) * 8;
    }

    bf16x8 ra[4], rb[WN];
#pragma unroll
    for (int j = 0; j < 4; j++)
        ra[j] = *(const bf16x8*)(Ab + (long)srow[j] * lda + scol[j]);
#pragma unroll
    for (int j = 0; j < WN; j++)
        rb[j] = *(const bf16x8*)(Bb + (long)srow[j] * ldb + scol[j]);

    for (int kt = 0; kt < K; kt += 64) {
#pragma unroll
        for (int j = 0; j < 4; j++)
            *(bf16x8*)&As[(t + j * 256) * 8] = ra[j];
#pragma unroll
        for (int j = 0; j < WN; j++)
            *(bf16x8*)&Bs[(t + j * 256) * 8] = rb[j];
        __syncthreads();

        if (kt + 64 < K) {
            const int kn = kt + 64;
#pragma unroll
            for (int j = 0; j < 4; j++)
                ra[j] = *(const bf16x8*)(Ab + (long)srow[j] * lda + kn + scol[j]);
#pragma unroll
            for (int j = 0; j < WN; j++)
                rb[j] = *(const bf16x8*)(Bb + (long)srow[j] * ldb + kn + scol[j]);
        }

#pragma unroll
        for (int kk = 0; kk < 2; kk++) {
            const int cc = (cc0 ^ (kk * 4)) * 8;
            bf16x8 bfr[WN];
#pragma unroll
            for (int j = 0; j < WN; j++)
                bfr[j] = *(const bf16x8*)&Bs[(wn * WN * 16 + j * 16 + frow) * 64 + cc];
#pragma unroll
            for (int i = 0; i < 4; i++) {
                bf16x8 af = *(const bf16x8*)&As[(wm * 64 + i * 16 + frow) * 64 + cc];
#pragma unroll
                for (int j = 0; j < WN; j++)
                    acc[i][j] = __builtin_amdgcn_mfma_f32_16x16x32_bf16(af, bfr[j], acc[i][j], 0, 0, 0);
            }
        }
        __syncthreads();
    }

    const int m_base = by * 128 + wm * 64;
    const int n_base = bx * (32 * WN) + wn * (16 * WN);

    if (EPI == 0) {
        const int seg = n_base / 768;
        const float* bp = (seg == 0) ? b0 : (seg == 1) ? b1 : b2;
        u16* C = (u16*)Cv + z * batchC;
#pragma unroll
        for (int j = 0; j < WN; j++) {
            const int col = n_base + j * 16 + frow;
            const float bb = bp[col - seg * 768];
#pragma unroll
            for (int i = 0; i < 4; i++) {
                const int row0 = m_base + i * 16 + quad * 4;
#pragma unroll
                for (int r = 0; r < 4; r++)
                    C[(long)(row0 + r) * ldc + col] = f2bf(acc[i][j][r] + bb);
            }
        }
    } else if (EPI == 1) {
        u16* C = (u16*)Cv + z * batchC;
        float rowpart[4][4];
#pragma unroll
        for (int i = 0; i < 4; i++)
#pragma unroll
            for (int r = 0; r < 4; r++) rowpart[i][r] = 0.f;
#pragma unroll
        for (int i = 0; i < 4; i++) {
            const int row0 = m_base + i * 16 + quad * 4;
#pragma unroll
            for (int j = 0; j < WN; j++) {
                const int col = n_base + j * 16 + frow;
#pragma unroll
                for (int r = 0; r < 4; r++) {
                    float e = exp2f(acc[i][j][r] * s2);
                    C[(long)(row0 + r) * ldc + col] = f2bf(e);
                    rowpart[i][r] += e;
                }
            }
        }
#pragma unroll
        for (int i = 0; i < 4; i++)
#pragma unroll
            for (int r = 0; r < 4; r++) {
                float v = rowpart[i][r];
                v += __shfl_xor(v, 1); v += __shfl_xor(v, 2);
                v += __shfl_xor(v, 4); v += __shfl_xor(v, 8);
                if (frow == 0)
                    atomicAdd(&rs[z * 4096 + m_base + i * 16 + quad * 4 + r], v);
            }
    } else {
        float* C = (float*)Cv + z * batchC;
#pragma unroll
        for (int i = 0; i < 4; i++) {
            const int row0 = m_base + i * 16 + quad * 4;
            float inv[4];
#pragma unroll
            for (int r = 0; r < 4; r++) inv[r] = 1.0f / rs[z * 4096 + row0 + r];
#pragma unroll
            for (int j = 0; j < WN; j++) {
                const int col = n_base + j * 16 + frow;
#pragma unroll
                for (int r = 0; r < 4; r++)
                    C[(long)(row0 + r) * ldc + col] = acc[i][j][r] * inv[r];
            }
        }
    }
}

// ==================== R7: 8-phase 256x256 GEMM (T2+T3+T4+T5) ====================
// 512 thr = 8 waves (2M x 4N), wave tile 128x64, BK=64 as two K-halves of 32.
// LDS 128 KiB: lds[buf:2][region:4][8192 u16]; regions 0=A-K0 1=A-K1 2=B-K0 3=B-K1.
// Region layout: 256 rows x 32k stored as 128-byte "lines" of 2 rows; global chunk
// (row,c) at line row>>1, slot (row&1)*4 + (c ^ ((row>>1)&3)).  16-lane read groups
// hit 8 distinct 16B bank-groups (2-way = free, same as the measured-0 2-phase swz).
// global_load_lds 16B: LINEAR dest (wave base + lane*16), pre-swizzled global SOURCE
// (rule 21).  Region ring in consumption order  B-K0 < A-K0 < B-K1 < A-K1:
//   phase (t,0) stages A-K1 of t+1 -> buf[t+1&1];  phases (t,1/2/3) stage
//   B-K0/A-K0/B-K1 of t+2 -> buf[t&1] (each region's reads finished one phase ago).
// vmcnt(6) ONCE per K-tile (3 half-regions in flight, never 0 in steady state);
// raw s_barrier (no counter drain -- this is what breaks the ~900 TF 2-phase ceiling);
// setprio(1) around each 16-MFMA cluster.
// EPI: 1 = exp2(acc*s2) bf16 + rowsum atomics;  2 = acc/rs[row] fp32 out.
__device__ __forceinline__ void gload16(const u16* src, u16* dst) {
    __builtin_amdgcn_global_load_lds((const __attribute__((address_space(1))) void*)src,
                                     (__attribute__((address_space(3))) void*)dst,
                                     16, 0, 0);
}

template <int EPI, int NBX, int NBY, int NT>
__global__ __launch_bounds__(512, 2) void gemm8_kernel(
        const u16* __restrict__ A, const u16* __restrict__ B, void* __restrict__ Cv,
        float* __restrict__ rs, float s2,
        int lda, int ldb, int ldc, long batchA, long batchB, long batchC) {
    static_assert(NT >= 3, "pipeline needs >=3 K-tiles");
    __shared__ __align__(16) u16 lds[2][4][8192];

    constexpr int NWG = NBX * NBY * 4;
    const int lin = blockIdx.x;
    const int swz = (lin & 7) * (NWG / 8) + (lin >> 3);     // XCD-contiguous (NWG%8==0)
    const int bz  = swz / (NBX * NBY);
    const int rr_ = swz % (NBX * NBY);
    const int by  = rr_ / NBX, bx = rr_ % NBX;

    const int t_   = threadIdx.x;
    const int lane = t_ & 63;
    const int wave = t_ >> 6;
    const int wm = wave >> 2, wn = wave & 3;                // 2 x 4 wave grid
    const int frow = lane & 15, quad = lane >> 4;

    const u16* Ab = A + (long)bz * batchA + (long)by * 256 * lda;
    const u16* Bb = B + (long)bz * batchB + (long)bx * 256 * ldb;

    // staging source map (pre-swizzled global address; LDS dest is linear)
    const int srow = ((t_ >> 3) << 1) | ((t_ >> 2) & 1);    // 0..127 (+ j*128)
    const int scol = ((t_ & 3) ^ ((t_ >> 3) & 3)) * 8;      // u16 chunk offset in K-half
    const int dstu = wave * 512;                            // wave-uniform dest (u16)

    // fragment read offset (per thread, region-relative, u16)
    const int rdoff = (frow >> 1) * 64
                    + ((frow & 1) * 4 + (quad ^ ((frow >> 1) & 3))) * 8;
    const int aoff = wm * 128 * 32 + rdoff;                 // + sub*2048 + i*512
    const int boff = wn * 64 * 32 + rdoff;                  // + j*512

    f32x4 acc[8][4];
#pragma unroll
    for (int i = 0; i < 8; i++)
#pragma unroll
        for (int j = 0; j < 4; j++)
#pragma unroll
            for (int e = 0; e < 4; e++) acc[i][j][e] = 0.f;

    auto STAGE = [&](int buf, int reg, const u16* gb, int ld_, int kofs) {
#pragma unroll
        for (int j = 0; j < 2; ++j) {
            const u16* sp = gb + (long)(srow + j * 128) * ld_ + kofs + scol;
            gload16(sp, &lds[buf][reg][dstu + j * 4096]);
        }
    };

    // prologue: K-tile 0 complete (consumption order), K-tile 1 first 3 regions
    STAGE(0, 2, Bb, ldb, 0);
    STAGE(0, 0, Ab, lda, 0);
    STAGE(0, 3, Bb, ldb, 32);
    STAGE(0, 1, Ab, lda, 32);
    STAGE(1, 2, Bb, ldb, 64);
    STAGE(1, 0, Ab, lda, 64);
    STAGE(1, 3, Bb, ldb, 96);
    asm volatile("s_waitcnt vmcnt(6)" ::: "memory");        // K-tile 0 landed
    __builtin_amdgcn_s_barrier();

#define MFMA16(SUB)                                                              \
    __builtin_amdgcn_s_setprio(1);                                               \
    _Pragma("unroll")                                                            \
    for (int i = 0; i < 4; ++i)                                                  \
        _Pragma("unroll")                                                        \
        for (int j = 0; j < 4; ++j)                                              \
            acc[(SUB) * 4 + i][j] = __builtin_amdgcn_mfma_f32_16x16x32_bf16(     \
                a[i], b[j], acc[(SUB) * 4 + i][j], 0, 0, 0);                     \
    __builtin_amdgcn_s_setprio(0);

#pragma unroll 2
    for (int t = 0; t < NT; ++t) {
        const int cur = t & 1, nxt = cur ^ 1;
        const u16* A0 = (const u16*)lds[cur][0];
        const u16* A1 = (const u16*)lds[cur][1];
        const u16* B0 = (const u16*)lds[cur][2];
        const u16* B1 = (const u16*)lds[cur][3];
        bf16x8 a[4], b[4];

        // -- phase 0: rows 0-63 x K0 --------------------------------------
#pragma unroll
        for (int i = 0; i < 4; ++i) a[i] = *(const bf16x8*)&A0[aoff + i * 512];
#pragma unroll
        for (int j = 0; j < 4; ++j) b[j] = *(const bf16x8*)&B0[boff + j * 512];
        if (t + 1 < NT) STAGE(nxt, 1, Ab, lda, (t + 1) * 64 + 32);   // A-K1(t+1)
        __builtin_amdgcn_s_barrier();
        asm volatile("s_waitcnt lgkmcnt(0)" ::: "memory");
        MFMA16(0)
        __builtin_amdgcn_s_barrier();

        // -- phase 1: rows 64-127 x K0 ------------------------------------
#pragma unroll
        for (int i = 0; i < 4; ++i) a[i] = *(const bf16x8*)&A0[aoff + 2048 + i * 512];
        if (t + 2 < NT) STAGE(cur, 2, Bb, ldb, (t + 2) * 64);        // B-K0(t+2)
        __builtin_amdgcn_s_barrier();
        asm volatile("s_waitcnt lgkmcnt(0)" ::: "memory");
        MFMA16(1)
        __builtin_amdgcn_s_barrier();

        // -- phase 2: rows 0-63 x K1 --------------------------------------
#pragma unroll
        for (int i = 0; i < 4; ++i) a[i] = *(const bf16x8*)&A1[aoff + i * 512];
#pragma unroll
        for (int j = 0; j < 4; ++j) b[j] = *(const bf16x8*)&B1[boff + j * 512];
        if (t + 2 < NT) STAGE(cur, 0, Ab, lda, (t + 2) * 64);        // A-K0(t+2)
        __builtin_amdgcn_s_barrier();
        asm volatile("s_waitcnt lgkmcnt(0)" ::: "memory");
        MFMA16(0)
        __builtin_amdgcn_s_barrier();

        // -- phase 3: rows 64-127 x K1 ------------------------------------
#pragma unroll
        for (int i = 0; i < 4; ++i) a[i] = *(const bf16x8*)&A1[aoff + 2048 + i * 512];
        if (t + 2 < NT) STAGE(cur, 3, Bb, ldb, (t + 2) * 64 + 32);   // B-K1(t+2)
        __builtin_amdgcn_s_barrier();
        asm volatile("s_waitcnt lgkmcnt(0)" ::: "memory");
        MFMA16(1)
        if (t + 2 < NT)      asm volatile("s_waitcnt vmcnt(6)" ::: "memory");
        else if (t + 1 < NT) asm volatile("s_waitcnt vmcnt(0)" ::: "memory");
        __builtin_amdgcn_s_barrier();
    }
#undef MFMA16

    // epilogue: C/D layout col = frow (n), row = quad*4 + reg (m)  [m89-verified]
    const int m_base = by * 256 + wm * 128;
    const int n_base = bx * 256 + wn * 64;
    const long z = bz;

    if (EPI == 1) {
        u16* C = (u16*)Cv + z * batchC;
#pragma unroll
        for (int ig = 0; ig < 8; ++ig) {
            const int row0 = m_base + ig * 16 + quad * 4;
            float rp[4] = {0.f, 0.f, 0.f, 0.f};
#pragma unroll
            for (int j = 0; j < 4; ++j) {
                const int col = n_base + j * 16 + frow;
#pragma unroll
                for (int r = 0; r < 4; ++r) {
                    float e = exp2f(acc[ig][j][r] * s2);
                    C[(long)(row0 + r) * ldc + col] = f2bf(e);
                    rp[r] += e;
                }
            }
#pragma unroll
            for (int r = 0; r < 4; ++r) {
                float v = rp[r];
                v += __shfl_xor(v, 1); v += __shfl_xor(v, 2);
                v += __shfl_xor(v, 4); v += __shfl_xor(v, 8);
                if (frow == 0) atomicAdd(&rs[z * 4096 + row0 + r], v);
            }
        }
    } else {
        float* C = (float*)Cv + z * batchC;
#pragma unroll
        for (int ig = 0; ig < 8; ++ig) {
            const int row0 = m_base + ig * 16 + quad * 4;
            float inv[4];
#pragma unroll
            for (int r = 0; r < 4; ++r) inv[r] = 1.0f / rs[z * 4096 + row0 + r];
#pragma unroll
            for (int j = 0; j < 4; ++j) {
                const int col = n_base + j * 16 + frow;
#pragma unroll
                for (int r = 0; r < 4; ++r)
                    C[(long)(row0 + r) * ldc + col] = acc[ig][j][r] * inv[r];
            }
        }
    }
}

extern "C" void kernel_launch(void* const* d_in, const int* in_sizes, int n_in,
                              void* d_out, int out_size, void* d_ws, size_t ws_size,
                              hipStream_t stream) {
    const float* x  = (const float*)d_in[0];
    const float* Wq = (const float*)d_in[1];
    const float* bq = (const float*)d_in[2];
    const float* Wk = (const float*)d_in[3];
    const float* bk = (const float*)d_in[4];
    const float* Wv = (const float*)d_in[5];
    const float* bv = (const float*)d_in[6];
    float* out = (float*)d_out;

    // B=4, S=4096, D=768; 16384 tokens. Workspace layout (total 238,419,968 B):
    //  @0          : xb bf16 [16384][768]      (25,165,824)  -- dead after proj; Vt reuses it
    //  @25,165,824 : QKV bf16 [16384][2304]    (75,497,472)
    //  @100,663,296: E bf16 [4][4096][4096]    (134,217,728)
    //  @234,881,024: Wqkv bf16 [2304][768]     (3,538,944)   -- dead after proj;
    //                 rowsum fp32[16384] (65,536) aliases its head, zeroed in transpose
    uint8_t* ws = (uint8_t*)d_ws;
    u16*   xb   = (u16*)(ws + 0);
    u16*   Vt   = (u16*)(ws + 0);
    u16*   QKV  = (u16*)(ws + 25165824);
    u16*   E    = (u16*)(ws + 100663296);
    u16*   Wqkv = (u16*)(ws + 234881024);
    float* rsum = (float*)(ws + 234881024);

    // 1) casts
    cast_bf16_kernel<<<12288, 256, 0, stream>>>(x, xb, 3145728);
    cast3_bf16_kernel<<<dim3(576, 3), 256, 0, stream>>>(Wq, Wk, Wv, Wqkv);

    // 2) fused QKV projection: [16384,768] x [2304,768]^T + bias -> QKV bf16 (ldc 2304)
    gemm_bt_kernel<0, 4, 18, 6, 2304, 128, 3><<<2304, 256, 0, stream>>>(
        xb, Wqkv, QKV, bq, bk, bv, nullptr, 0.f, 768, 768, 768, 2304, 0, 0, 0);

    // 3) V transpose per batch (V = QKV cols [1536,2304), ld 2304) -> Vt[e][s]; zero rowsum
    transpose_bf16_kernel<<<dim3(24, 128, 4), 256, 0, stream>>>(QKV + 1536, Vt, rsum);

    // 4) E = exp(scale * Q K^T) + rowsum atomics  -- 8-phase 256^2, grid 16*16*4=1024
    //    s2 = (1/sqrt(768)) * log2(e)
    gemm8_kernel<1, 16, 16, 12><<<1024, 512, 0, stream>>>(
        QKV, QKV + 768, E, rsum, 0.05205954822032348f,
        2304, 2304, 4096, (long)4096 * 2304, (long)4096 * 2304, (long)4096 * 4096);

    // 5) O = (E Vt^T) / rowsum -> fp32 out  -- 8-phase 256^2, grid 3*16*4=192
    gemm8_kernel<2, 3, 16, 64><<<192, 512, 0, stream>>>(
        E, Vt, out, rsum, 0.f,
        4096, 4096, 768, (long)4096 * 4096, (long)768 * 4096, (long)4096 * 768);
}

// Round 2
// 409.486 us; speedup vs baseline: 1.0720x; 1.0720x over previous
//
#include <hip/hip_runtime.h>
#include <stdint.h>

typedef unsigned short u16;
typedef __attribute__((ext_vector_type(8))) short    bf16x8;   // 8 bf16 in 4 VGPRs
typedef __attribute__((ext_vector_type(4))) float    f32x4;

// ---------- helpers ----------
__device__ __forceinline__ u16 f2bf(float f) {           // fp32 -> bf16, round-nearest-even
    unsigned u = __float_as_uint(f);
    u = (u + 0x7fffu + ((u >> 16) & 1u)) >> 16;
    return (u16)u;
}

// ---------- fused fp32 -> bf16 cast: x (12288 blocks) + Wq|Wk|Wv (1728 blocks) ----------
// single launch; W blocks write into one concatenated [2304][768] bf16 buffer
__global__ __launch_bounds__(256) void cast_all_kernel(const float* __restrict__ x,
                                                       const float* __restrict__ w0,
                                                       const float* __restrict__ w1,
                                                       const float* __restrict__ w2,
                                                       u16* __restrict__ xb,
                                                       u16* __restrict__ wb) {
    const int b = blockIdx.x;
    if (b < 12288) {                                  // x: 3145728 float4
        int i = b * 256 + threadIdx.x;
        float4 f = ((const float4*)x)[i];
        ushort4 o;
        o.x = f2bf(f.x); o.y = f2bf(f.y); o.z = f2bf(f.z); o.w = f2bf(f.w);
        ((ushort4*)xb)[i] = o;
    } else {                                          // W: 3 x 576 blocks of 256 float4
        const int i2 = b - 12288;
        const int w  = i2 / 576;                      // 0..2
        const int blk = i2 - w * 576;
        const float* src = (w == 0) ? w0 : (w == 1) ? w1 : w2;
        int i = blk * 256 + threadIdx.x;              // 576*256 = 147456 = 768*768/4
        float4 f = ((const float4*)src)[i];
        ushort4 o;
        o.x = f2bf(f.x); o.y = f2bf(f.y); o.z = f2bf(f.z); o.w = f2bf(f.w);
        ((ushort4*)wb)[(size_t)w * 147456 + i] = o;
    }
}

// ---------- bf16 32x32-tiled transpose: Vt[b][e][s] = V[b][s][e] (ld_in=2304) ----------
// also zeroes the rowsum buffer (it aliases the dead weight buffer; runs after proj GEMM)
__global__ __launch_bounds__(256) void transpose_bf16_kernel(const u16* __restrict__ V,
                                                             u16* __restrict__ Vt,
                                                             float* __restrict__ rsum) {
    __shared__ u16 tile[32][33];
    const int t = threadIdx.x;
    if (blockIdx.x == 0 && blockIdx.z == 0) {
        int idx = blockIdx.y * 256 + t;
        if (idx < 16384) rsum[idx] = 0.f;
    }
    const size_t z = blockIdx.z;
    const u16* Vb  = V  + z * (size_t)4096 * 2304;
    u16*       Vtb = Vt + z * (size_t)768 * 4096;
    const int c0 = blockIdx.x * 32;           // D (col) tile
    const int r0 = blockIdx.y * 32;           // S (row) tile
    const int lr = t >> 3;                    // 0..31
    const int lc = (t & 7) * 4;               // 0..28
    ushort4 in = *(const ushort4*)&Vb[(size_t)(r0 + lr) * 2304 + c0 + lc];
    tile[lr][lc + 0] = in.x; tile[lr][lc + 1] = in.y;
    tile[lr][lc + 2] = in.z; tile[lr][lc + 3] = in.w;
    __syncthreads();
    ushort4 o;
    o.x = tile[lc + 0][lr]; o.y = tile[lc + 1][lr];
    o.z = tile[lc + 2][lr]; o.w = tile[lc + 3][lr];
    *(ushort4*)&Vtb[(size_t)(c0 + lr) * 4096 + r0 + lc] = o;
}

// ---------- GEMM, BK=64, reg-staged prefetch: C[m][n] = sum_k A[m][k]*B[n][k] ----------
// Block tile 128 x (32*WN); 4 waves in 2x2; wave tile 64 x (16*WN) via 4xWN MFMA 16x16x32.
//   WN=8 (fat): only for long-K + large-grid cases (QK: 24 iters, 2048 blocks).
//   WN=4 (thin): proj (short K=768 -> tail/prologue dominate at 2 blk/CU; R6 measured
//                regression with fat) and PV (N=768 caps the grid).
// Pipeline: tile k+1 global->VGPR during tile k's MFMA phase, ds_write after barrier.
// LDS XOR swizzle: chunk (r,c) holds global chunk (r, c^(r&7)) -- conflict-free (R4: 0).
// EPI: 0 = +bias[col] (b0/b1/b2 per 768-col segment), bf16 out            (QKV projection)
//      1 = exp2(acc*s2), bf16 out, atomicAdd row sums into rs             (QK^T -> E)
//      2 = acc * (1/rs[row]), fp32 out                                    (E*Vt -> O)
// Grid 1D = NGRID, two-level XCD swizzle: lin%8 = XCD; bx-group of GRP innermost,
// strips middle, groups outer -> concurrent working set sized to the 4 MB per-XCD L2.
template <int EPI, int WN, int NBX, int GRP, int NGRID, int NBY, int MINW>
__global__ __launch_bounds__(256, MINW) void gemm_bt_kernel(
        const u16* __restrict__ A, const u16* __restrict__ B, void* __restrict__ Cv,
        const float* __restrict__ b0, const float* __restrict__ b1, const float* __restrict__ b2,
        float* __restrict__ rs, float s2, int K,
        int lda, int ldb, int ldc, long batchA, long batchB, long batchC) {
    __shared__ __align__(16) u16 As[128 * 64];
    __shared__ __align__(16) u16 Bs[32 * WN * 64];

    constexpr int SPX = NGRID / (8 * NBX);        // strips per XCD
    const int lin = blockIdx.x;
    const int c = lin & 7, p = lin >> 3;
    const int bxi = p % GRP;
    const int rest = p / GRP;
    const int s = rest % SPX;
    const int g = rest / SPX;
    const int bx = g * GRP + bxi;
    const int strip = c * SPX + s;
    const int by = strip % NBY;
    const int bz = strip / NBY;

    const int t = threadIdx.x;
    const long z = bz;
    const u16* Ab = A + z * batchA + (long)by * 128 * lda;
    const u16* Bb = B + z * batchB + (long)bx * (32 * WN) * ldb;

    const int lane = t & 63;
    const int wave = t >> 6;
    const int wm = wave >> 1, wn = wave & 1;      // 2x2 wave grid
    const int quad = lane >> 4;
    const int frow = lane & 15;
    const int cc0 = quad ^ (frow & 7);            // swizzled chunk col for k-chunk 0

    f32x4 acc[4][WN];
#pragma unroll
    for (int i = 0; i < 4; i++)
#pragma unroll
        for (int j = 0; j < WN; j++)
#pragma unroll
            for (int e = 0; e < 4; e++) acc[i][j][e] = 0.f;

    // staging map: dest chunk d=(r,c8) sources global chunk (r, c8^(r&7)).
    // A: 1024 chunks (j<4); B: 256*WN chunks (j<WN). Same formula, shared arrays.
    int srow[WN], scol[WN];
#pragma unroll
    for (int j = 0; j < WN; j++) {
        const int d = t + j * 256;
        srow[j] = d >> 3;
        scol[j] = ((d & 7) ^ (srow[j] & 7)) * 8;
    }

    // register-staged prefetch buffers
    bf16x8 ra[4], rb[WN];
#pragma unroll
    for (int j = 0; j < 4; j++)
        ra[j] = *(const bf16x8*)(Ab + (long)srow[j] * lda + scol[j]);
#pragma unroll
    for (int j = 0; j < WN; j++)
        rb[j] = *(const bf16x8*)(Bb + (long)srow[j] * ldb + scol[j]);

    for (int kt = 0; kt < K; kt += 64) {
        // commit prefetched tile to LDS (loads were issued one compute-phase ago)
#pragma unroll
        for (int j = 0; j < 4; j++)
            *(bf16x8*)&As[(t + j * 256) * 8] = ra[j];
#pragma unroll
        for (int j = 0; j < WN; j++)
            *(bf16x8*)&Bs[(t + j * 256) * 8] = rb[j];
        __syncthreads();

        // issue next tile's global loads; they fly during the MFMA phase below
        if (kt + 64 < K) {
            const int kn = kt + 64;
#pragma unroll
            for (int j = 0; j < 4; j++)
                ra[j] = *(const bf16x8*)(Ab + (long)srow[j] * lda + kn + scol[j]);
#pragma unroll
            for (int j = 0; j < WN; j++)
                rb[j] = *(const bf16x8*)(Bb + (long)srow[j] * ldb + kn + scol[j]);
        }

#pragma unroll
        for (int kk = 0; kk < 2; kk++) {
            const int cc = (cc0 ^ (kk * 4)) * 8;
            bf16x8 bfr[WN];
#pragma unroll
            for (int j = 0; j < WN; j++)
                bfr[j] = *(const bf16x8*)&Bs[(wn * WN * 16 + j * 16 + frow) * 64 + cc];
#pragma unroll
            for (int i = 0; i < 4; i++) {
                bf16x8 af = *(const bf16x8*)&As[(wm * 64 + i * 16 + frow) * 64 + cc];
#pragma unroll
                for (int j = 0; j < WN; j++)
                    acc[i][j] = __builtin_amdgcn_mfma_f32_16x16x32_bf16(af, bfr[j], acc[i][j], 0, 0, 0);
            }
        }
        __syncthreads();   // LDS readers done before next iter's ds_write
    }

    // epilogue: C/D layout col = lane&15 (n), row = quad*4 + reg (m)  [m89-verified]
    const int m_base = by * 128 + wm * 64;
    const int n_base = bx * (32 * WN) + wn * (16 * WN);

    if (EPI == 0) {
        const int seg = n_base / 768;             // uniform per wave; tile fits one segment
        const float* bp = (seg == 0) ? b0 : (seg == 1) ? b1 : b2;
        u16* C = (u16*)Cv + z * batchC;
#pragma unroll
        for (int j = 0; j < WN; j++) {
            const int col = n_base + j * 16 + frow;
            const float bb = bp[col - seg * 768];
#pragma unroll
            for (int i = 0; i < 4; i++) {
                const int row0 = m_base + i * 16 + quad * 4;
#pragma unroll
                for (int r = 0; r < 4; r++)
                    C[(long)(row0 + r) * ldc + col] = f2bf(acc[i][j][r] + bb);
            }
        }
    } else if (EPI == 1) {
        u16* C = (u16*)Cv + z * batchC;
        float rowpart[4][4];
#pragma unroll
        for (int i = 0; i < 4; i++)
#pragma unroll
            for (int r = 0; r < 4; r++) rowpart[i][r] = 0.f;
#pragma unroll
        for (int i = 0; i < 4; i++) {
            const int row0 = m_base + i * 16 + quad * 4;
#pragma unroll
            for (int j = 0; j < WN; j++) {
                const int col = n_base + j * 16 + frow;
#pragma unroll
                for (int r = 0; r < 4; r++) {
                    float e = exp2f(acc[i][j][r] * s2);
                    C[(long)(row0 + r) * ldc + col] = f2bf(e);
                    rowpart[i][r] += e;
                }
            }
        }
        // reduce each row's partial over the 16 frow lanes, then one atomic per row
#pragma unroll
        for (int i = 0; i < 4; i++)
#pragma unroll
            for (int r = 0; r < 4; r++) {
                float v = rowpart[i][r];
                v += __shfl_xor(v, 1); v += __shfl_xor(v, 2);
                v += __shfl_xor(v, 4); v += __shfl_xor(v, 8);
                if (frow == 0)
                    atomicAdd(&rs[z * 4096 + m_base + i * 16 + quad * 4 + r], v);
            }
    } else {
        float* C = (float*)Cv + z * batchC;
#pragma unroll
        for (int i = 0; i < 4; i++) {
            const int row0 = m_base + i * 16 + quad * 4;
            float inv[4];
#pragma unroll
            for (int r = 0; r < 4; r++) inv[r] = 1.0f / rs[z * 4096 + row0 + r];
#pragma unroll
            for (int j = 0; j < WN; j++) {
                const int col = n_base + j * 16 + frow;
#pragma unroll
                for (int r = 0; r < 4; r++)
                    C[(long)(row0 + r) * ldc + col] = acc[i][j][r] * inv[r];
            }
        }
    }
}

extern "C" void kernel_launch(void* const* d_in, const int* in_sizes, int n_in,
                              void* d_out, int out_size, void* d_ws, size_t ws_size,
                              hipStream_t stream) {
    const float* x  = (const float*)d_in[0];
    const float* Wq = (const float*)d_in[1];
    const float* bq = (const float*)d_in[2];
    const float* Wk = (const float*)d_in[3];
    const float* bk = (const float*)d_in[4];
    const float* Wv = (const float*)d_in[5];
    const float* bv = (const float*)d_in[6];
    float* out = (float*)d_out;

    // B=4, S=4096, D=768; 16384 tokens. Workspace layout (total 238,419,968 B):
    //  @0          : xb bf16 [16384][768]      (25,165,824)  -- dead after proj; Vt reuses it
    //  @25,165,824 : QKV bf16 [16384][2304]    (75,497,472)
    //  @100,663,296: E bf16 [4][4096][4096]    (134,217,728)
    //  @234,881,024: Wqkv bf16 [2304][768]     (3,538,944)   -- dead after proj;
    //                 rowsum fp32[16384] (65,536) aliases its head, zeroed in transpose
    uint8_t* ws = (uint8_t*)d_ws;
    u16*   xb   = (u16*)(ws + 0);
    u16*   Vt   = (u16*)(ws + 0);
    u16*   QKV  = (u16*)(ws + 25165824);
    u16*   E    = (u16*)(ws + 100663296);
    u16*   Wqkv = (u16*)(ws + 234881024);
    float* rsum = (float*)(ws + 234881024);

    // 1) casts (x + all three W) in one launch: 12288 + 3*576 = 14016 blocks
    cast_all_kernel<<<14016, 256, 0, stream>>>(x, Wq, Wk, Wv, xb, Wqkv);

    // 2) fused QKV projection: [16384,768] x [2304,768]^T + bias -> QKV bf16 (ldc 2304)
    //    THIN tile (R5-proven): short K=768 punishes fat tiles (R6: +28 us). GRP=6.
    gemm_bt_kernel<0, 4, 18, 6, 2304, 128, 3><<<2304, 256, 0, stream>>>(
        xb, Wqkv, QKV, bq, bk, bv, nullptr, 0.f, 768, 768, 768, 2304, 0, 0, 0);

    // 3) V transpose per batch (V = QKV cols [1536,2304), ld 2304) -> Vt[e][s]; zero rowsum
    transpose_bf16_kernel<<<dim3(24, 128, 4), 256, 0, stream>>>(QKV + 1536, Vt, rsum);

    // 4) E = exp(scale * Q K^T) (per batch, 4096x4096, K=768) + rowsum atomics
    //    s2 = (1/sqrt(768)) * log2(e); FAT tile 128x256 (R6-proven: 150->135 us)
    gemm_bt_kernel<1, 8, 16, 4, 2048, 32, 2><<<2048, 256, 0, stream>>>(
        QKV, QKV + 768, E, nullptr, nullptr, nullptr, rsum, 0.05205954822032348f,
        768, 2304, 2304, 4096, (long)4096 * 2304, (long)4096 * 2304, (long)4096 * 4096);

    // 5) O = (E Vt^T) / rowsum -> fp32 out (per batch, M=4096, N=768, K=4096)
    //    THIN tile: N=768 -> 6 bx, 768 blocks = exactly 3/CU resident, zero tail
    gemm_bt_kernel<2, 4, 6, 6, 768, 32, 3><<<768, 256, 0, stream>>>(
        E, Vt, out, nullptr, nullptr, nullptr, rsum, 0.f,
        4096, 4096, 4096, 768, (long)4096 * 4096, (long)768 * 4096, (long)4096 * 768);
}

// Round 4
// 407.786 us; speedup vs baseline: 1.0765x; 1.0042x over previous
//
#include <hip/hip_runtime.h>
#include <stdint.h>

typedef unsigned short u16;
typedef __attribute__((ext_vector_type(8))) short    bf16x8;   // 8 bf16 in 4 VGPRs
typedef __attribute__((ext_vector_type(4))) float    f32x4;

// ---------- helpers ----------
__device__ __forceinline__ u16 f2bf(float f) {           // fp32 -> bf16, round-nearest-even
    unsigned u = __float_as_uint(f);
    u = (u + 0x7fffu + ((u >> 16) & 1u)) >> 16;
    return (u16)u;
}

// ---------- fused fp32 -> bf16 cast: x (12288 blocks) + Wq|Wk|Wv (1728 blocks) ----------
__global__ __launch_bounds__(256) void cast_all_kernel(const float* __restrict__ x,
                                                       const float* __restrict__ w0,
                                                       const float* __restrict__ w1,
                                                       const float* __restrict__ w2,
                                                       u16* __restrict__ xb,
                                                       u16* __restrict__ wb) {
    const int b = blockIdx.x;
    if (b < 12288) {                                  // x: 3145728 float4
        int i = b * 256 + threadIdx.x;
        float4 f = ((const float4*)x)[i];
        ushort4 o;
        o.x = f2bf(f.x); o.y = f2bf(f.y); o.z = f2bf(f.z); o.w = f2bf(f.w);
        ((ushort4*)xb)[i] = o;
    } else {                                          // W: 3 x 576 blocks of 256 float4
        const int i2 = b - 12288;
        const int w  = i2 / 576;                      // 0..2
        const int blk = i2 - w * 576;
        const float* src = (w == 0) ? w0 : (w == 1) ? w1 : w2;
        int i = blk * 256 + threadIdx.x;              // 576*256 = 147456 = 768*768/4
        float4 f = ((const float4*)src)[i];
        ushort4 o;
        o.x = f2bf(f.x); o.y = f2bf(f.y); o.z = f2bf(f.z); o.w = f2bf(f.w);
        ((ushort4*)wb)[(size_t)w * 147456 + i] = o;
    }
}

// ---------- bf16 32x32-tiled transpose: Vt[b][e][s] = V[b][s][e] (ld_in=2304) ----------
// also zeroes the rowsum buffer (it aliases the dead weight buffer; runs after proj GEMM)
__global__ __launch_bounds__(256) void transpose_bf16_kernel(const u16* __restrict__ V,
                                                             u16* __restrict__ Vt,
                                                             float* __restrict__ rsum) {
    __shared__ u16 tile[32][33];
    const int t = threadIdx.x;
    if (blockIdx.x == 0 && blockIdx.z == 0) {
        int idx = blockIdx.y * 256 + t;
        if (idx < 16384) rsum[idx] = 0.f;
    }
    const size_t z = blockIdx.z;
    const u16* Vb  = V  + z * (size_t)4096 * 2304;
    u16*       Vtb = Vt + z * (size_t)768 * 4096;
    const int c0 = blockIdx.x * 32;           // D (col) tile
    const int r0 = blockIdx.y * 32;           // S (row) tile
    const int lr = t >> 3;                    // 0..31
    const int lc = (t & 7) * 4;               // 0..28
    ushort4 in = *(const ushort4*)&Vb[(size_t)(r0 + lr) * 2304 + c0 + lc];
    tile[lr][lc + 0] = in.x; tile[lr][lc + 1] = in.y;
    tile[lr][lc + 2] = in.z; tile[lr][lc + 3] = in.w;
    __syncthreads();
    ushort4 o;
    o.x = tile[lc + 0][lr]; o.y = tile[lc + 1][lr];
    o.z = tile[lc + 2][lr]; o.w = tile[lc + 3][lr];
    *(ushort4*)&Vtb[(size_t)(c0 + lr) * 4096 + r0 + lc] = o;
}

// ---------- 2-phase GEMM (proj + PV; R5/R6-proven) ----------
template <int EPI, int WN, int NBX, int GRP, int NGRID, int NBY, int MINW>
__global__ __launch_bounds__(256, MINW) void gemm_bt_kernel(
        const u16* __restrict__ A, const u16* __restrict__ B, void* __restrict__ Cv,
        const float* __restrict__ b0, const float* __restrict__ b1, const float* __restrict__ b2,
        float* __restrict__ rs, float s2, int K,
        int lda, int ldb, int ldc, long batchA, long batchB, long batchC) {
    __shared__ __align__(16) u16 As[128 * 64];
    __shared__ __align__(16) u16 Bs[32 * WN * 64];

    constexpr int SPX = NGRID / (8 * NBX);        // strips per XCD
    const int lin = blockIdx.x;
    const int c = lin & 7, p = lin >> 3;
    const int bxi = p % GRP;
    const int rest = p / GRP;
    const int s = rest % SPX;
    const int g = rest / SPX;
    const int bx = g * GRP + bxi;
    const int strip = c * SPX + s;
    const int by = strip % NBY;
    const int bz = strip / NBY;

    const int t = threadIdx.x;
    const long z = bz;
    const u16* Ab = A + z * batchA + (long)by * 128 * lda;
    const u16* Bb = B + z * batchB + (long)bx * (32 * WN) * ldb;

    const int lane = t & 63;
    const int wave = t >> 6;
    const int wm = wave >> 1, wn = wave & 1;      // 2x2 wave grid
    const int quad = lane >> 4;
    const int frow = lane & 15;
    const int cc0 = quad ^ (frow & 7);            // swizzled chunk col for k-chunk 0

    f32x4 acc[4][WN];
#pragma unroll
    for (int i = 0; i < 4; i++)
#pragma unroll
        for (int j = 0; j < WN; j++)
#pragma unroll
            for (int e = 0; e < 4; e++) acc[i][j][e] = 0.f;

    int srow[WN], scol[WN];
#pragma unroll
    for (int j = 0; j < WN; j++) {
        const int d = t + j * 256;
        srow[j] = d >> 3;
        scol[j] = ((d & 7) ^ (srow[j] & 7)) * 8;
    }

    bf16x8 ra[4], rb[WN];
#pragma unroll
    for (int j = 0; j < 4; j++)
        ra[j] = *(const bf16x8*)(Ab + (long)srow[j] * lda + scol[j]);
#pragma unroll
    for (int j = 0; j < WN; j++)
        rb[j] = *(const bf16x8*)(Bb + (long)srow[j] * ldb + scol[j]);

    for (int kt = 0; kt < K; kt += 64) {
#pragma unroll
        for (int j = 0; j < 4; j++)
            *(bf16x8*)&As[(t + j * 256) * 8] = ra[j];
#pragma unroll
        for (int j = 0; j < WN; j++)
            *(bf16x8*)&Bs[(t + j * 256) * 8] = rb[j];
        __syncthreads();

        if (kt + 64 < K) {
            const int kn = kt + 64;
#pragma unroll
            for (int j = 0; j < 4; j++)
                ra[j] = *(const bf16x8*)(Ab + (long)srow[j] * lda + kn + scol[j]);
#pragma unroll
            for (int j = 0; j < WN; j++)
                rb[j] = *(const bf16x8*)(Bb + (long)srow[j] * ldb + kn + scol[j]);
        }

#pragma unroll
        for (int kk = 0; kk < 2; kk++) {
            const int cc = (cc0 ^ (kk * 4)) * 8;
            bf16x8 bfr[WN];
#pragma unroll
            for (int j = 0; j < WN; j++)
                bfr[j] = *(const bf16x8*)&Bs[(wn * WN * 16 + j * 16 + frow) * 64 + cc];
#pragma unroll
            for (int i = 0; i < 4; i++) {
                bf16x8 af = *(const bf16x8*)&As[(wm * 64 + i * 16 + frow) * 64 + cc];
#pragma unroll
                for (int j = 0; j < WN; j++)
                    acc[i][j] = __builtin_amdgcn_mfma_f32_16x16x32_bf16(af, bfr[j], acc[i][j], 0, 0, 0);
            }
        }
        __syncthreads();
    }

    const int m_base = by * 128 + wm * 64;
    const int n_base = bx * (32 * WN) + wn * (16 * WN);

    if (EPI == 0) {
        const int seg = n_base / 768;
        const float* bp = (seg == 0) ? b0 : (seg == 1) ? b1 : b2;
        u16* C = (u16*)Cv + z * batchC;
#pragma unroll
        for (int j = 0; j < WN; j++) {
            const int col = n_base + j * 16 + frow;
            const float bb = bp[col - seg * 768];
#pragma unroll
            for (int i = 0; i < 4; i++) {
                const int row0 = m_base + i * 16 + quad * 4;
#pragma unroll
                for (int r = 0; r < 4; r++)
                    C[(long)(row0 + r) * ldc + col] = f2bf(acc[i][j][r] + bb);
            }
        }
    } else if (EPI == 1) {
        u16* C = (u16*)Cv + z * batchC;
        float rowpart[4][4];
#pragma unroll
        for (int i = 0; i < 4; i++)
#pragma unroll
            for (int r = 0; r < 4; r++) rowpart[i][r] = 0.f;
#pragma unroll
        for (int i = 0; i < 4; i++) {
            const int row0 = m_base + i * 16 + quad * 4;
#pragma unroll
            for (int j = 0; j < WN; j++) {
                const int col = n_base + j * 16 + frow;
#pragma unroll
                for (int r = 0; r < 4; r++) {
                    float e = exp2f(acc[i][j][r] * s2);
                    C[(long)(row0 + r) * ldc + col] = f2bf(e);
                    rowpart[i][r] += e;
                }
            }
        }
#pragma unroll
        for (int i = 0; i < 4; i++)
#pragma unroll
            for (int r = 0; r < 4; r++) {
                float v = rowpart[i][r];
                v += __shfl_xor(v, 1); v += __shfl_xor(v, 2);
                v += __shfl_xor(v, 4); v += __shfl_xor(v, 8);
                if (frow == 0)
                    atomicAdd(&rs[z * 4096 + m_base + i * 16 + quad * 4 + r], v);
            }
    } else {
        float* C = (float*)Cv + z * batchC;
#pragma unroll
        for (int i = 0; i < 4; i++) {
            const int row0 = m_base + i * 16 + quad * 4;
            float inv[4];
#pragma unroll
            for (int r = 0; r < 4; r++) inv[r] = 1.0f / rs[z * 4096 + row0 + r];
#pragma unroll
            for (int j = 0; j < WN; j++) {
                const int col = n_base + j * 16 + frow;
#pragma unroll
                for (int r = 0; r < 4; r++)
                    C[(long)(row0 + r) * ldc + col] = acc[i][j][r] * inv[r];
            }
        }
    }
}

// ==================== R4 (= R3 resubmit): 8-phase 256x256 GEMM, asm ds_read (QK only) ====
// R1 failure diagnosed: C++-level LDS reads after global_load_lds intrinsics force the
// compiler to insert s_waitcnt vmcnt(0) per phase (alias conservatism) -> prefetch queue
// drained every phase -> per-K-tile HBM serialization (3.5 us/K-tile measured).
// Fix: fragment loads via inline-asm ds_read_b128 (invisible to waitcnt insertion);
// ordering restored manually: s_waitcnt lgkmcnt(0) + sched_barrier(0) before each MFMA
// cluster (rule #18).  Ring re-verified under counted vmcnt: at end of iter t-1, the 6
// outstanding loads are {B-K0(t+1), A-K0(t+1), B-K1(t+1)}; everything iter t reads has
// landed.  Two-level XCD swizzle (R0-proven): lin%8 = XCD, bx-group of GRP innermost.
__device__ __forceinline__ void gload16(const u16* src, u16* dst) {
    __builtin_amdgcn_global_load_lds((const __attribute__((address_space(1))) void*)src,
                                     (__attribute__((address_space(3))) void*)dst,
                                     16, 0, 0);
}

template <int IMM>
__device__ __forceinline__ bf16x8 dsr128(uint32_t addr) {
    bf16x8 r;
    asm volatile("ds_read_b128 %0, %1 offset:%2" : "=v"(r) : "v"(addr), "i"(IMM));
    return r;
}

#define LDS_ADDR(BUF, REG) \
    ((uint32_t)(uintptr_t)(__attribute__((address_space(3))) void*)&lds[BUF][REG][0])

template <int EPI, int NBX, int NBY, int GRP, int NGRID, int NT>
__global__ __launch_bounds__(512, 2) void gemm8_kernel(
        const u16* __restrict__ A, const u16* __restrict__ B, void* __restrict__ Cv,
        float* __restrict__ rs, float s2,
        int lda, int ldb, int ldc, long batchA, long batchB, long batchC) {
    static_assert(NT >= 3 && (NT % 2) == 0, "pipeline needs even NT >= 4");
    __shared__ __align__(16) u16 lds[2][4][8192];

    constexpr int SPX = NGRID / (8 * NBX);        // strips per XCD
    const int lin = blockIdx.x;
    const int c = lin & 7, p = lin >> 3;
    const int bxi = p % GRP;
    const int rest = p / GRP;
    const int s = rest % SPX;
    const int g = rest / SPX;
    const int bx = g * GRP + bxi;
    const int strip = c * SPX + s;
    const int by = strip % NBY;
    const int bz = strip / NBY;

    const int t_   = threadIdx.x;
    const int lane = t_ & 63;
    const int wave = t_ >> 6;
    const int wm = wave >> 2, wn = wave & 3;                // 2 x 4 wave grid
    const int frow = lane & 15, quad = lane >> 4;

    const u16* Ab = A + (long)bz * batchA + (long)by * 256 * lda;
    const u16* Bb = B + (long)bz * batchB + (long)bx * 256 * ldb;

    // staging source map (pre-swizzled global address; LDS dest is linear)
    const int srow = ((t_ >> 3) << 1) | ((t_ >> 2) & 1);    // 0..127 (+ j*128)
    const int scol = ((t_ & 3) ^ ((t_ >> 3) & 3)) * 8;      // u16 chunk offset in K-half
    const int dstu = wave * 512;                            // wave-uniform dest (u16)

    // fragment read offset (per thread, region-relative, BYTES)
    const uint32_t rdoff2 = (uint32_t)(((frow >> 1) * 64
                          + ((frow & 1) * 4 + (quad ^ ((frow >> 1) & 3))) * 8) * 2);
    const uint32_t aoff2 = (uint32_t)(wm * 128 * 32 * 2) + rdoff2;  // + sub*4096 + i*1024 (imm)
    const uint32_t boff2 = (uint32_t)(wn * 64 * 32 * 2) + rdoff2;   // + j*1024 (imm)

    f32x4 acc[8][4];
#pragma unroll
    for (int i = 0; i < 8; i++)
#pragma unroll
        for (int j = 0; j < 4; j++)
#pragma unroll
            for (int e = 0; e < 4; e++) acc[i][j][e] = 0.f;

    auto STAGE = [&](int buf, int reg, const u16* gb, int ld_, int kofs) {
#pragma unroll
        for (int j = 0; j < 2; ++j) {
            const u16* sp = gb + (long)(srow + j * 128) * ld_ + kofs + scol;
            gload16(sp, &lds[buf][reg][dstu + j * 4096]);
        }
    };

    // prologue: K-tile 0 complete (consumption order), K-tile 1 first 3 regions
    STAGE(0, 2, Bb, ldb, 0);
    STAGE(0, 0, Ab, lda, 0);
    STAGE(0, 3, Bb, ldb, 32);
    STAGE(0, 1, Ab, lda, 32);
    STAGE(1, 2, Bb, ldb, 64);
    STAGE(1, 0, Ab, lda, 64);
    STAGE(1, 3, Bb, ldb, 96);
    asm volatile("s_waitcnt vmcnt(6)" ::: "memory");        // K-tile 0 landed
    __builtin_amdgcn_s_barrier();

#define MFMA16(SUB)                                                              \
    __builtin_amdgcn_s_setprio(1);                                               \
    _Pragma("unroll")                                                            \
    for (int i = 0; i < 4; ++i)                                                  \
        _Pragma("unroll")                                                        \
        for (int j = 0; j < 4; ++j)                                              \
            acc[(SUB) * 4 + i][j] = __builtin_amdgcn_mfma_f32_16x16x32_bf16(     \
                a[i], b[j], acc[(SUB) * 4 + i][j], 0, 0, 0);                     \
    __builtin_amdgcn_s_setprio(0);

#define SYNC_PRE_MFMA()                                      \
    __builtin_amdgcn_s_barrier();                            \
    asm volatile("s_waitcnt lgkmcnt(0)" ::: "memory");       \
    __builtin_amdgcn_sched_barrier(0);

#pragma unroll 2
    for (int t = 0; t < NT; ++t) {
        const int cur = t & 1, nxt = cur ^ 1;
        bf16x8 a[4], b[4];

        // -- phase 0: rows 0-63 x K0 (reads A reg0, B reg2) ----------------
        {
            const uint32_t aA = LDS_ADDR(cur, 0) + aoff2;
            const uint32_t aB = LDS_ADDR(cur, 2) + boff2;
            a[0] = dsr128<0>(aA);    a[1] = dsr128<1024>(aA);
            a[2] = dsr128<2048>(aA); a[3] = dsr128<3072>(aA);
            b[0] = dsr128<0>(aB);    b[1] = dsr128<1024>(aB);
            b[2] = dsr128<2048>(aB); b[3] = dsr128<3072>(aB);
        }
        if (t + 1 < NT) STAGE(nxt, 1, Ab, lda, (t + 1) * 64 + 32);   // A-K1(t+1)
        SYNC_PRE_MFMA()
        MFMA16(0)
        __builtin_amdgcn_s_barrier();

        // -- phase 1: rows 64-127 x K0 (reads A reg0 sub1; b persists) -----
        {
            const uint32_t aA = LDS_ADDR(cur, 0) + aoff2;
            a[0] = dsr128<4096>(aA); a[1] = dsr128<5120>(aA);
            a[2] = dsr128<6144>(aA); a[3] = dsr128<7168>(aA);
        }
        if (t + 2 < NT) STAGE(cur, 2, Bb, ldb, (t + 2) * 64);        // B-K0(t+2)
        SYNC_PRE_MFMA()
        MFMA16(1)
        __builtin_amdgcn_s_barrier();

        // -- phase 2: rows 0-63 x K1 (reads A reg1, B reg3) ----------------
        {
            const uint32_t aA = LDS_ADDR(cur, 1) + aoff2;
            const uint32_t aB = LDS_ADDR(cur, 3) + boff2;
            a[0] = dsr128<0>(aA);    a[1] = dsr128<1024>(aA);
            a[2] = dsr128<2048>(aA); a[3] = dsr128<3072>(aA);
            b[0] = dsr128<0>(aB);    b[1] = dsr128<1024>(aB);
            b[2] = dsr128<2048>(aB); b[3] = dsr128<3072>(aB);
        }
        if (t + 2 < NT) STAGE(cur, 0, Ab, lda, (t + 2) * 64);        // A-K0(t+2)
        SYNC_PRE_MFMA()
        MFMA16(0)
        __builtin_amdgcn_s_barrier();

        // -- phase 3: rows 64-127 x K1 (reads A reg1 sub1; b persists) -----
        {
            const uint32_t aA = LDS_ADDR(cur, 1) + aoff2;
            a[0] = dsr128<4096>(aA); a[1] = dsr128<5120>(aA);
            a[2] = dsr128<6144>(aA); a[3] = dsr128<7168>(aA);
        }
        if (t + 2 < NT) STAGE(cur, 3, Bb, ldb, (t + 2) * 64 + 32);   // B-K1(t+2)
        SYNC_PRE_MFMA()
        MFMA16(1)
        if (t + 2 < NT)      asm volatile("s_waitcnt vmcnt(6)" ::: "memory");
        else if (t + 1 < NT) asm volatile("s_waitcnt vmcnt(0)" ::: "memory");
        __builtin_amdgcn_s_barrier();
    }
#undef MFMA16
#undef SYNC_PRE_MFMA

    // epilogue: C/D layout col = frow (n), row = quad*4 + reg (m)  [m89-verified]
    const int m_base = by * 256 + wm * 128;
    const int n_base = bx * 256 + wn * 64;
    const long z = bz;

    if (EPI == 1) {
        u16* C = (u16*)Cv + z * batchC;
#pragma unroll
        for (int ig = 0; ig < 8; ++ig) {
            const int row0 = m_base + ig * 16 + quad * 4;
            float rp[4] = {0.f, 0.f, 0.f, 0.f};
#pragma unroll
            for (int j = 0; j < 4; ++j) {
                const int col = n_base + j * 16 + frow;
#pragma unroll
                for (int r = 0; r < 4; ++r) {
                    float e = exp2f(acc[ig][j][r] * s2);
                    C[(long)(row0 + r) * ldc + col] = f2bf(e);
                    rp[r] += e;
                }
            }
#pragma unroll
            for (int r = 0; r < 4; ++r) {
                float v = rp[r];
                v += __shfl_xor(v, 1); v += __shfl_xor(v, 2);
                v += __shfl_xor(v, 4); v += __shfl_xor(v, 8);
                if (frow == 0) atomicAdd(&rs[z * 4096 + row0 + r], v);
            }
        }
    } else {
        float* C = (float*)Cv + z * batchC;
#pragma unroll
        for (int ig = 0; ig < 8; ++ig) {
            const int row0 = m_base + ig * 16 + quad * 4;
            float inv[4];
#pragma unroll
            for (int r = 0; r < 4; ++r) inv[r] = 1.0f / rs[z * 4096 + row0 + r];
#pragma unroll
            for (int j = 0; j < 4; ++j) {
                const int col = n_base + j * 16 + frow;
#pragma unroll
                for (int r = 0; r < 4; ++r)
                    C[(long)(row0 + r) * ldc + col] = acc[ig][j][r] * inv[r];
            }
        }
    }
}

extern "C" void kernel_launch(void* const* d_in, const int* in_sizes, int n_in,
                              void* d_out, int out_size, void* d_ws, size_t ws_size,
                              hipStream_t stream) {
    const float* x  = (const float*)d_in[0];
    const float* Wq = (const float*)d_in[1];
    const float* bq = (const float*)d_in[2];
    const float* Wk = (const float*)d_in[3];
    const float* bk = (const float*)d_in[4];
    const float* Wv = (const float*)d_in[5];
    const float* bv = (const float*)d_in[6];
    float* out = (float*)d_out;

    // B=4, S=4096, D=768; 16384 tokens. Workspace layout (total 238,419,968 B):
    //  @0          : xb bf16 [16384][768]      (25,165,824)  -- dead after proj; Vt reuses it
    //  @25,165,824 : QKV bf16 [16384][2304]    (75,497,472)
    //  @100,663,296: E bf16 [4][4096][4096]    (134,217,728)
    //  @234,881,024: Wqkv bf16 [2304][768]     (3,538,944)   -- dead after proj;
    //                 rowsum fp32[16384] (65,536) aliases its head, zeroed in transpose
    uint8_t* ws = (uint8_t*)d_ws;
    u16*   xb   = (u16*)(ws + 0);
    u16*   Vt   = (u16*)(ws + 0);
    u16*   QKV  = (u16*)(ws + 25165824);
    u16*   E    = (u16*)(ws + 100663296);
    u16*   Wqkv = (u16*)(ws + 234881024);
    float* rsum = (float*)(ws + 234881024);

    // 1) casts (x + all three W) in one launch: 12288 + 3*576 = 14016 blocks
    cast_all_kernel<<<14016, 256, 0, stream>>>(x, Wq, Wk, Wv, xb, Wqkv);

    // 2) fused QKV projection: [16384,768] x [2304,768]^T + bias -> QKV bf16 (ldc 2304)
    gemm_bt_kernel<0, 4, 18, 6, 2304, 128, 3><<<2304, 256, 0, stream>>>(
        xb, Wqkv, QKV, bq, bk, bv, nullptr, 0.f, 768, 768, 768, 2304, 0, 0, 0);

    // 3) V transpose per batch (V = QKV cols [1536,2304), ld 2304) -> Vt[e][s]; zero rowsum
    transpose_bf16_kernel<<<dim3(24, 128, 4), 256, 0, stream>>>(QKV + 1536, Vt, rsum);

    // 4) E = exp(scale * Q K^T) + rowsum atomics -- 8-phase 256^2, asm ds_read
    //    grid 16 bx * 16 by * 4 bz = 1024; GRP=4; s2 = (1/sqrt(768)) * log2(e)
    gemm8_kernel<1, 16, 16, 4, 1024, 12><<<1024, 512, 0, stream>>>(
        QKV, QKV + 768, E, rsum, 0.05205954822032348f,
        2304, 2304, 4096, (long)4096 * 2304, (long)4096 * 2304, (long)4096 * 4096);

    // 5) O = (E Vt^T) / rowsum -> fp32 out (per batch, M=4096, N=768, K=4096)
    //    THIN tile 2-phase: N=768 -> 6 bx, 768 blocks = exactly 3/CU resident, zero tail
    gemm_bt_kernel<2, 4, 6, 6, 768, 32, 3><<<768, 256, 0, stream>>>(
        E, Vt, out, nullptr, nullptr, nullptr, rsum, 0.f,
        4096, 4096, 4096, 768, (long)4096 * 4096, (long)768 * 4096, (long)4096 * 768);
}